// Round 5
// baseline (27.772 us; speedup 1.0000x reference)
//
#include <hip/hip_runtime.h>

#define NROWS 8192
#define INCH 10
#define NQKV 33
#define OUTCH 11
#define SPLIT 16
#define KB 512            // k-rows per block (single LDS stage)
#define QBLK 256          // q-rows per block (4 waves x 64)

typedef short short8 __attribute__((ext_vector_type(8)));
typedef float f32x16 __attribute__((ext_vector_type(16)));
typedef unsigned int uvec4 __attribute__((ext_vector_type(4)));

// ws byte layout:
//   QB_OFF: Q bf16 [NROWS][16ch] rows of 32B (scale*log2e folded into q)
//   KB_OFF: K bf16 planes [2][NROWS][16B]: plane c holds ch 8c..8c+7
//   VT_OFF: V^T bf16 interleaved: 16B unit u=(k>>3)*16+d holds V[k8*8+slot][d],
//           d=0..10 v, d=11 ones (softmax denom), d=12..15 zero
//   PART_OFF: f32 [SPLIT][NROWS][12] per-k-chunk partials (o0..o10, l)
#define QB_OFF   0
#define KB_OFF   (NROWS * 32)
#define VT_OFF   (2 * NROWS * 32)
#define PART_OFF (3 * NROWS * 32)

// v_permlane32_swap_b32 a, b:
//   a' = {a.lo32lanes, b.lo32lanes}, b' = {a.hi32lanes, b.hi32lanes}
#define SWAP32(a, b) asm("v_permlane32_swap_b32 %0, %1" : "+v"(a), "+v"(b))

__device__ inline unsigned short f2bf(float f) {
  unsigned u = __float_as_uint(f);
  unsigned r = (u + 0x7FFFu + ((u >> 16) & 1u)) >> 16;  // RNE
  return (unsigned short)r;
}

// ---------------------------------------------------------------------------
// Kernel A: LayerNorm + Linear(10->33); emit bf16 Q rows, K planes, V^T.
// ---------------------------------------------------------------------------
__global__ __launch_bounds__(64) void qkv_ln_kernel(
    const float* __restrict__ x, const float* __restrict__ gamma,
    const float* __restrict__ beta, const float* __restrict__ W,
    char* __restrict__ ws) {
  __shared__ float sW[NQKV * INCH];
  __shared__ float sg[INCH];
  __shared__ float sb[INCH];
  int tid = threadIdx.x;
  for (int i = tid; i < NQKV * INCH; i += 64) sW[i] = W[i];
  if (tid < INCH) { sg[tid] = gamma[tid]; sb[tid] = beta[tid]; }
  __syncthreads();

  int row = blockIdx.x * 64 + tid;
  const float2* x2 = (const float2*)x;  // rows are 40B = 5 float2, 8B aligned
  float xv[INCH];
#pragma unroll
  for (int j = 0; j < 5; ++j) {
    float2 t = x2[row * 5 + j];
    xv[2 * j] = t.x;
    xv[2 * j + 1] = t.y;
  }

  float mu = 0.f;
#pragma unroll
  for (int i = 0; i < INCH; ++i) mu += xv[i];
  mu *= (1.0f / INCH);
  float var = 0.f;
#pragma unroll
  for (int i = 0; i < INCH; ++i) { float d = xv[i] - mu; var += d * d; }
  var *= (1.0f / INCH);
  float rstd = rsqrtf(var + 1e-5f);
  float h[INCH];
#pragma unroll
  for (int i = 0; i < INCH; ++i) h[i] = (xv[i] - mu) * rstd * sg[i] + sb[i];

  float acc[NQKV];
#pragma unroll
  for (int oc = 0; oc < NQKV; ++oc) {
    float s = 0.f;
#pragma unroll
    for (int i = 0; i < INCH; ++i) s += h[i] * sW[oc * INCH + i];
    acc[oc] = s;
  }

  // exp(s*scale) = exp2(s*scale*log2e): fold into q.
  const float QSC = 0.31622776601683794f * 1.4426950408889634f;

  unsigned short e[16];
  unsigned qw[8];
  // ---- Q row ----
#pragma unroll
  for (int i = 0; i < 16; ++i) e[i] = (i < OUTCH) ? f2bf(acc[i] * QSC) : 0;
#pragma unroll
  for (int i = 0; i < 8; ++i)
    qw[i] = (unsigned)e[2 * i] | ((unsigned)e[2 * i + 1] << 16);
  uint4* Qb = (uint4*)(ws + QB_OFF);
  Qb[row * 2 + 0] = make_uint4(qw[0], qw[1], qw[2], qw[3]);
  Qb[row * 2 + 1] = make_uint4(qw[4], qw[5], qw[6], qw[7]);
  // ---- K planes ----
#pragma unroll
  for (int i = 0; i < 16; ++i) e[i] = (i < OUTCH) ? f2bf(acc[OUTCH + i]) : 0;
#pragma unroll
  for (int i = 0; i < 8; ++i)
    qw[i] = (unsigned)e[2 * i] | ((unsigned)e[2 * i + 1] << 16);
  uint4* Kb = (uint4*)(ws + KB_OFF);
  Kb[row] = make_uint4(qw[0], qw[1], qw[2], qw[3]);          // plane 0
  Kb[NROWS + row] = make_uint4(qw[4], qw[5], qw[6], qw[7]);  // plane 1
  // ---- V^T scatter (2B stores into interleaved units) ----
  unsigned short* VTu = (unsigned short*)(ws + VT_OFF);
  int u0 = (row >> 3) * 16;
  int slot = row & 7;
#pragma unroll
  for (int d = 0; d < 16; ++d) {
    unsigned short v;
    if (d < OUTCH)       v = f2bf(acc[2 * OUTCH + d]);
    else if (d == OUTCH) v = 0x3F80;  // ones column -> softmax denominator
    else                 v = 0;
    VTu[(u0 + d) * 8 + slot] = v;
  }
}

// ---------------------------------------------------------------------------
// Kernel B: MFMA flash attention partial. No row-max (|s|<=~13, fp32-safe,
// softmax shift-invariant). Wave owns 64 q-rows = 2 subtiles of 32: one
// K-frag + V-frag read feeds 2 QK MFMAs + 4 PV MFMAs (halves LDS traffic).
// K LDS layout is planar [2][KB][16B] -> contiguous-16B/lane ds_read_b128
// (conflict-free; row-major 32B rows were an 8-way conflict).
//   S^T = mfma_32x32x16(A=K, B=Q): lane owns q=lane&31, k=(r&3)+8*(r>>2)+4h.
//   p = exp2(S); v_perm bf16 pack; v_permlane32_swap -> PV A-frags.
//   O += mfma_32x32x16(A=P, B=V) x2. V ones-column gives l for free.
// ---------------------------------------------------------------------------
__global__ __launch_bounds__(256) void attn_kernel(const char* __restrict__ ws,
                                                   float* __restrict__ part) {
  __shared__ uint4 sK[2 * KB];   // 16 KB: K planes [2][KB]
  __shared__ uint4 sVT[KB * 2];  // 16 KB: V^T interleaved units

  const int tid = threadIdx.x;
  const int lane = tid & 63;
  const int wv = tid >> 6;
  const int h = lane >> 5;
  const int l31 = lane & 31;
  const int qc = blockIdx.x >> 4;  // SPLIT=16
  const int kc = blockIdx.x & 15;
  const int kt0 = kc * KB;
  const int q0 = qc * QBLK + wv * 64;

  const uint4* gK = (const uint4*)(ws + KB_OFF);
  const uint4* gV = (const uint4*)(ws + VT_OFF) + kt0 * 2;

  // async global->LDS staging, 16B/lane, wave-linear dest
#pragma unroll
  for (int c = 0; c < 2; ++c) {
#pragma unroll
    for (int i = 0; i < 2; ++i) {
      int o = wv * 64 + 256 * i;
      __builtin_amdgcn_global_load_lds(
          (const __attribute__((address_space(1))) void*)(gK + c * NROWS + kt0 + o + lane),
          (__attribute__((address_space(3))) void*)(sK + c * KB + o), 16, 0, 0);
    }
  }
#pragma unroll
  for (int i = 0; i < 4; ++i) {
    int o = wv * 64 + 256 * i;
    __builtin_amdgcn_global_load_lds(
        (const __attribute__((address_space(1))) void*)(gV + o + lane),
        (__attribute__((address_space(3))) void*)(sVT + o), 16, 0, 0);
  }

  // Q fragments: lane holds Q[q0 + u*32 + (lane&31)][ch 8h..8h+7]
  const char* Qb = ws + QB_OFF;
  short8 qf0 = *(const short8*)(Qb + (q0 + l31) * 32 + h * 16);
  short8 qf1 = *(const short8*)(Qb + (q0 + 32 + l31) * 32 + h * 16);

  f32x16 oacc0, oacc1, zf;
#pragma unroll
  for (int r = 0; r < 16; ++r) { oacc0[r] = 0.f; oacc1[r] = 0.f; zf[r] = 0.f; }

  __syncthreads();

  for (int it = 0; it < KB / 32; ++it) {
    // K fragment: plane h, rows it*32 + l31 -> contiguous 16B/lane
    short8 kf = *(const short8*)((const char*)sK + h * (KB * 16) +
                                 (it * 32 + l31) * 16);
    f32x16 s0 = __builtin_amdgcn_mfma_f32_32x32x16_bf16(kf, qf0, zf, 0, 0, 0);
    f32x16 s1 = __builtin_amdgcn_mfma_f32_32x32x16_bf16(kf, qf1, zf, 0, 0, 0);

    // V fragments: lane holds V[k=16c+8h+i][d=lane&15]
    const char* vb = (const char*)sVT;
    short8 v0 = *(const short8*)(vb + (it * 4 + h) * 256 + (lane & 15) * 16);
    short8 v1 = *(const short8*)(vb + (it * 4 + 2 + h) * 256 + (lane & 15) * 16);

#define PK(a, b) __builtin_amdgcn_perm(__float_as_uint(b), __float_as_uint(a), 0x07060302u)
#define MKFRAG(sv, A0, A1)                                                   \
  {                                                                          \
    float p[16];                                                             \
    _Pragma("unroll") for (int r = 0; r < 16; ++r)                           \
        p[r] = __builtin_amdgcn_exp2f(sv[r]);                                \
    unsigned P01 = PK(p[0], p[1]), P23 = PK(p[2], p[3]);                     \
    unsigned P45 = PK(p[4], p[5]), P67 = PK(p[6], p[7]);                     \
    unsigned P89 = PK(p[8], p[9]), Pab = PK(p[10], p[11]);                   \
    unsigned Pcd = PK(p[12], p[13]), Pef = PK(p[14], p[15]);                 \
    SWAP32(P01, P45);                                                        \
    SWAP32(P23, P67);                                                        \
    SWAP32(P89, Pcd);                                                        \
    SWAP32(Pab, Pef);                                                        \
    uvec4 c0 = {P01, P23, P45, P67};                                         \
    uvec4 c1 = {P89, Pab, Pcd, Pef};                                         \
    A0 = __builtin_bit_cast(short8, c0);                                     \
    A1 = __builtin_bit_cast(short8, c1);                                     \
  }

    short8 a00, a01, a10, a11;
    MKFRAG(s0, a00, a01)
    MKFRAG(s1, a10, a11)
#undef MKFRAG
#undef PK

    oacc0 = __builtin_amdgcn_mfma_f32_32x32x16_bf16(a00, v0, oacc0, 0, 0, 0);
    oacc0 = __builtin_amdgcn_mfma_f32_32x32x16_bf16(a01, v1, oacc0, 0, 0, 0);
    oacc1 = __builtin_amdgcn_mfma_f32_32x32x16_bf16(a10, v0, oacc1, 0, 0, 0);
    oacc1 = __builtin_amdgcn_mfma_f32_32x32x16_bf16(a11, v1, oacc1, 0, 0, 0);
  }

  // epilogue: per-(q,d) partial store; d = lane&31 < 12, q unique per (r,h)
  if (l31 < 12) {
#pragma unroll
    for (int r = 0; r < 16; ++r) {
      int q = (r & 3) + 8 * (r >> 2) + 4 * h;
      part[((size_t)kc * NROWS + q0 + q) * 12 + l31] = oacc0[r];
      part[((size_t)kc * NROWS + q0 + 32 + q) * 12 + l31] = oacc1[r];
    }
  }
}

// ---------------------------------------------------------------------------
// Kernel C: combine SPLIT partials and normalize.
// ---------------------------------------------------------------------------
__global__ __launch_bounds__(64) void norm_kernel(const float* __restrict__ part,
                                                  float* __restrict__ out) {
  int row = blockIdx.x * 64 + threadIdx.x;
  const float4* p4 = (const float4*)part;
  float r[12];
#pragma unroll
  for (int d = 0; d < 12; ++d) r[d] = 0.f;
#pragma unroll
  for (int kc = 0; kc < SPLIT; ++kc) {
    size_t b = ((size_t)kc * NROWS + row) * 3;
    float4 t0 = p4[b], t1 = p4[b + 1], t2 = p4[b + 2];
    r[0] += t0.x; r[1] += t0.y; r[2] += t0.z; r[3] += t0.w;
    r[4] += t1.x; r[5] += t1.y; r[6] += t1.z; r[7] += t1.w;
    r[8] += t2.x; r[9] += t2.y; r[10] += t2.z; r[11] += t2.w;
  }
  float inv = 1.0f / r[11];
  float* o = out + (size_t)row * OUTCH;
#pragma unroll
  for (int d = 0; d < OUTCH; ++d) o[d] = r[d] * inv;
}

extern "C" void kernel_launch(void* const* d_in, const int* in_sizes, int n_in,
                              void* d_out, int out_size, void* d_ws, size_t ws_size,
                              hipStream_t stream) {
  const float* x = (const float*)d_in[0];
  const float* gamma = (const float*)d_in[1];
  const float* beta = (const float*)d_in[2];
  const float* W = (const float*)d_in[3];
  char* ws = (char*)d_ws;  // needs 768 KB + 6.3 MB partials ~= 7.1 MB
  float* out = (float*)d_out;
  float* part = (float*)(ws + PART_OFF);

  qkv_ln_kernel<<<NROWS / 64, 64, 0, stream>>>(x, gamma, beta, W, ws);
  attn_kernel<<<(NROWS / QBLK) * SPLIT, 256, 0, stream>>>(ws, part);
  norm_kernel<<<NROWS / 64, 64, 0, stream>>>(part, out);
}